// Round 4
// baseline (159.069 us; speedup 1.0000x reference)
//
#include <hip/hip_runtime.h>
#include <hip/hip_bf16.h>

typedef __attribute__((ext_vector_type(8))) short bf16x8;
typedef __attribute__((ext_vector_type(4))) float f32x4;
typedef __attribute__((ext_vector_type(4))) short s16x4;

#define M_DIM 4096   // B*S = 2*2048
#define N_DIM 4096   // D_out
#define K_DIM 4096   // D_in
#define R_DIM 4

__device__ __forceinline__ short to_bf16(float f) {
    __hip_bfloat16 h = __float2bfloat16(f);
    return *reinterpret_cast<short*>(&h);
}

// ---------------------------------------------------------------------------
// Kernel 1: tB[r][i] = tanh(scale_B[r,i]); tAg[o][r] = tanh(scale_A[o,r])*g[r]
// ---------------------------------------------------------------------------
__global__ __launch_bounds__(256)
void k_prep(const float* __restrict__ sA, const float* __restrict__ sB,
            const float* __restrict__ g, float* __restrict__ tB,
            float* __restrict__ tAg) {
    int i = blockIdx.x * 256 + threadIdx.x;
    if (i < R_DIM * K_DIM) {
        tB[i] = tanhf(sB[i]);
    } else {
        int j = i - R_DIM * K_DIM;   // j = o*4 + r
        tAg[j] = tanhf(sA[j]) * g[j & 3];
    }
}

// ---------------------------------------------------------------------------
// Kernel 2: x_bf16[m,k] = (bf16) x[m,k]
// ---------------------------------------------------------------------------
__global__ __launch_bounds__(256)
void k_xcast(const float* __restrict__ x, __hip_bfloat16* __restrict__ xb) {
    const size_t i = ((size_t)blockIdx.x * 256 + threadIdx.x) << 3;
    float4 u = *(const float4*)&x[i];
    float4 v = *(const float4*)&x[i + 4];
    bf16x8 pk;
    pk[0] = to_bf16(u.x); pk[1] = to_bf16(u.y);
    pk[2] = to_bf16(u.z); pk[3] = to_bf16(u.w);
    pk[4] = to_bf16(v.x); pk[5] = to_bf16(v.y);
    pk[6] = to_bf16(v.z); pk[7] = to_bf16(v.w);
    *(bf16x8*)&xb[i] = pk;
}

// ---------------------------------------------------------------------------
// Kernel 3: W_eff[o,i] = weight[o,i] * sum_r tAg[o,r]*tB[r,i]  -> bf16
// ---------------------------------------------------------------------------
__global__ __launch_bounds__(256)
void k_weff(const float* __restrict__ w, const float* __restrict__ tB,
            const float* __restrict__ tAg, __hip_bfloat16* __restrict__ weff) {
    const int o = blockIdx.x;
    const float a0 = tAg[o * 4 + 0];
    const float a1 = tAg[o * 4 + 1];
    const float a2 = tAg[o * 4 + 2];
    const float a3 = tAg[o * 4 + 3];
#pragma unroll
    for (int it = 0; it < 4; ++it) {
        const int i = (it * 256 + (int)threadIdx.x) << 2;
        float4 wv = *(const float4*)&w[(size_t)o * K_DIM + i];
        float4 b0 = *(const float4*)&tB[0 * K_DIM + i];
        float4 b1 = *(const float4*)&tB[1 * K_DIM + i];
        float4 b2 = *(const float4*)&tB[2 * K_DIM + i];
        float4 b3 = *(const float4*)&tB[3 * K_DIM + i];
        float s0 = a0 * b0.x + a1 * b1.x + a2 * b2.x + a3 * b3.x;
        float s1 = a0 * b0.y + a1 * b1.y + a2 * b2.y + a3 * b3.y;
        float s2 = a0 * b0.z + a1 * b1.z + a2 * b2.z + a3 * b3.z;
        float s3 = a0 * b0.w + a1 * b1.w + a2 * b2.w + a3 * b3.w;
        s16x4 pk;
        pk[0] = to_bf16(wv.x * s0);
        pk[1] = to_bf16(wv.y * s1);
        pk[2] = to_bf16(wv.z * s2);
        pk[3] = to_bf16(wv.w * s3);
        *(s16x4*)&weff[(size_t)o * K_DIM + i] = pk;
    }
}

// ---------------------------------------------------------------------------
// Kernel 4: out = x_bf16 @ weff^T + bias — 256x256 8-phase, reg-frag pipelined.
// 8 waves (2M x 4N), BK=64, LDS = 2dbuf x 2half x {A,B} = 128KB.
// Per K-tile (4 phases): q0 reads its 12 frags in-phase; q1..q3 A-frags are
// prefetched in the post-MFMA region of the previous phase (double-buffered
// X/Y sets). Stage order + vmcnt(4) at q3 identical to the verified round-3
// schedule. sched_barrier(0) after each K-tile publication barrier pins q0
// reads below the vmcnt+barrier seam.
// ---------------------------------------------------------------------------
#define MFMA(A, B, C) __builtin_amdgcn_mfma_f32_16x16x32_bf16(A, B, C, 0, 0, 0)

#define MFMA_Q(q, A0, A1, A2, A3) \
    acc[2*(q)][0]   = MFMA(A0, b0, acc[2*(q)][0]); \
    acc[2*(q)][0]   = MFMA(A1, b1, acc[2*(q)][0]); \
    acc[2*(q)+1][0] = MFMA(A2, b0, acc[2*(q)+1][0]); \
    acc[2*(q)+1][0] = MFMA(A3, b1, acc[2*(q)+1][0]); \
    acc[2*(q)][1]   = MFMA(A0, b2, acc[2*(q)][1]); \
    acc[2*(q)][1]   = MFMA(A1, b3, acc[2*(q)][1]); \
    acc[2*(q)+1][1] = MFMA(A2, b2, acc[2*(q)+1][1]); \
    acc[2*(q)+1][1] = MFMA(A3, b3, acc[2*(q)+1][1]); \
    acc[2*(q)][2]   = MFMA(A0, b4, acc[2*(q)][2]); \
    acc[2*(q)][2]   = MFMA(A1, b5, acc[2*(q)][2]); \
    acc[2*(q)+1][2] = MFMA(A2, b4, acc[2*(q)+1][2]); \
    acc[2*(q)+1][2] = MFMA(A3, b5, acc[2*(q)+1][2]); \
    acc[2*(q)][3]   = MFMA(A0, b6, acc[2*(q)][3]); \
    acc[2*(q)][3]   = MFMA(A1, b7, acc[2*(q)][3]); \
    acc[2*(q)+1][3] = MFMA(A2, b6, acc[2*(q)+1][3]); \
    acc[2*(q)+1][3] = MFMA(A3, b7, acc[2*(q)+1][3]);

#define READ_A(d, q, R0, R1, R2, R3) \
    { const int Ab_ = ((d) * 2 + wr) * 8192; \
      R0 = FRAG(Ab_, (2*(q))   * 16 + l15, cb0); \
      R1 = FRAG(Ab_, (2*(q))   * 16 + l15, cb1); \
      R2 = FRAG(Ab_, (2*(q)+1) * 16 + l15, cb0); \
      R3 = FRAG(Ab_, (2*(q)+1) * 16 + l15, cb1); }

#define READ_B(d) \
    { const int Bb_ = 32768 + ((d) * 2 + (wc >> 1)) * 8192; \
      b0 = FRAG(Bb_, br0, cb0); b1 = FRAG(Bb_, br0, cb1); \
      b2 = FRAG(Bb_, br1, cb0); b3 = FRAG(Bb_, br1, cb1); \
      b4 = FRAG(Bb_, br2, cb0); b5 = FRAG(Bb_, br2, cb1); \
      b6 = FRAG(Bb_, br3, cb0); b7 = FRAG(Bb_, br3, cb1); }

// q0: in-phase reads (12) into X + B; MFMA q0 on X; post-prefetch q1 into Y
#define PH_FIRST(d, STAGE_STMT) \
    { STAGE_STMT; \
      READ_A(d, 0, x0, x1, x2, x3); \
      READ_B(d); \
      __builtin_amdgcn_s_barrier(); \
      __builtin_amdgcn_s_setprio(1); \
      MFMA_Q(0, x0, x1, x2, x3); \
      __builtin_amdgcn_s_setprio(0); \
      READ_A(d, 1, y0, y1, y2, y3); \
      __builtin_amdgcn_s_barrier(); }

// q: MFMA on CUR (prefetched last phase); post-prefetch q+1 into NXT
#define PH_MID(d, q, C0, C1, C2, C3, N0, N1, N2, N3, STAGE_STMT) \
    { STAGE_STMT; \
      __builtin_amdgcn_s_barrier(); \
      __builtin_amdgcn_s_setprio(1); \
      MFMA_Q(q, C0, C1, C2, C3); \
      __builtin_amdgcn_s_setprio(0); \
      READ_A(d, (q) + 1, N0, N1, N2, N3); \
      __builtin_amdgcn_s_barrier(); }

// q3: MFMA on CUR; vmcnt(4); publication barrier; motion fence
#define PH_LAST(C0, C1, C2, C3, STAGE_STMT) \
    { STAGE_STMT; \
      __builtin_amdgcn_s_barrier(); \
      __builtin_amdgcn_s_setprio(1); \
      MFMA_Q(3, C0, C1, C2, C3); \
      __builtin_amdgcn_s_setprio(0); \
      asm volatile("s_waitcnt vmcnt(4)" ::: "memory"); \
      __builtin_amdgcn_s_barrier(); \
      __builtin_amdgcn_sched_barrier(0); }

__global__ __launch_bounds__(512, 2)
void k_gemm8(const __hip_bfloat16* __restrict__ xb,
             const __hip_bfloat16* __restrict__ weff,
             const float* __restrict__ bias, float* __restrict__ out) {
    __shared__ short lds[65536];   // A halves: [0,32768) ; B halves: [32768,65536)

    const int tid  = threadIdx.x;
    const int lane = tid & 63;
    const int wid  = tid >> 6;
    const int wr   = wid >> 2;           // wave M row 0..1  (128 rows each)
    const int wc   = wid & 3;            // wave N col 0..3  (64 cols each)
    const int l15  = lane & 15;
    const int cb0  = (lane >> 4) << 4;   // ksub0 fragment col-byte
    const int cb1  = cb0 + 64;           // ksub1

    // XCD-aware bijective swizzle: nwg=256, 256 % 8 == 0
    const int bid = blockIdx.x;
    const int swz = (bid & 7) * 32 + (bid >> 3);
    const int m0g = (swz >> 4) << 8;
    const int n0g = (swz & 15) << 8;

    const int br0 = (wc & 1) * 64 + 0  + l15;
    const int br1 = (wc & 1) * 64 + 16 + l15;
    const int br2 = (wc & 1) * 64 + 32 + l15;
    const int br3 = (wc & 1) * 64 + 48 + l15;

    auto STAGE = [&](const __hip_bfloat16* __restrict__ src, int gr0, int k0, int base) {
#pragma unroll
        for (int p = 0; p < 2; ++p) {
            const int P    = p * 8192 + tid * 16;            // phys byte in half
            const int row  = P >> 7;
            const int colb = (P & 127) ^ ((row & 7) << 4);   // inverse-swizzled src
            const __hip_bfloat16* g = src + ((size_t)(gr0 + row) << 12) + (k0 + (colb >> 1));
            __builtin_amdgcn_global_load_lds(
                (const __attribute__((address_space(1))) void*)g,
                (__attribute__((address_space(3))) void*)&lds[base + (P >> 1)],
                16, 0, 0);
        }
    };

    auto FRAG = [&](int base, int row, int cb) -> bf16x8 {
        const int byte = ((((row << 7) + cb) ^ ((row & 7) << 4))) + base * 2;
        return *(const bf16x8*)((const char*)lds + byte);
    };

    f32x4 acc[8][4] = {};
    bf16x8 x0, x1, x2, x3, y0, y1, y2, y3;
    bf16x8 b0, b1, b2, b3, b4, b5, b6, b7;

    // prologue: K-tile0 A+B, K-tile1 B   (12 loads; B[1] stays in flight)
    STAGE(xb,   m0g,       0,  0);
    STAGE(xb,   m0g + 128, 0,  8192);
    STAGE(weff, n0g,       0,  32768);
    STAGE(weff, n0g + 128, 0,  40960);
    STAGE(weff, n0g,       64, 49152);
    STAGE(weff, n0g + 128, 64, 57344);
    asm volatile("s_waitcnt vmcnt(4)" ::: "memory");
    __builtin_amdgcn_s_barrier();
    __builtin_amdgcn_sched_barrier(0);

    for (int i = 0; i < 32; ++i) {
        const int t1k = (2 * i + 1) * 64;
        const int kA  = (2 * i + 2 < 64 ? 2 * i + 2 : 63) * 64;
        const int kB  = (2 * i + 3 < 64 ? 2 * i + 3 : 63) * 64;

        // ---- K-tile d0 ----
        PH_FIRST(0,                           STAGE(xb,   m0g,       t1k, 16384));
        PH_MID(0, 1, y0,y1,y2,y3, x0,x1,x2,x3, STAGE(xb,   m0g + 128, t1k, 24576));
        PH_MID(0, 2, x0,x1,x2,x3, y0,y1,y2,y3, STAGE(weff, n0g,       kA,  32768));
        PH_LAST(     y0,y1,y2,y3,              STAGE(weff, n0g + 128, kA,  40960));
        // ---- K-tile d1 ----
        PH_FIRST(1,                           STAGE(xb,   m0g,       kA,  0));
        PH_MID(1, 1, y0,y1,y2,y3, x0,x1,x2,x3, STAGE(xb,   m0g + 128, kA,  8192));
        PH_MID(1, 2, x0,x1,x2,x3, y0,y1,y2,y3, STAGE(weff, n0g,       kB,  49152));
        PH_LAST(     y0,y1,y2,y3,              STAGE(weff, n0g + 128, kB,  57344));
    }

    // epilogue: C/D map col=lane&15, row=(lane>>4)*4+j
#pragma unroll
    for (int n = 0; n < 4; ++n) {
        const int col = n0g + wc * 64 + n * 16 + l15;
        const float bv = bias[col];
#pragma unroll
        for (int m = 0; m < 8; ++m) {
            const int rbase = m0g + wr * 128 + m * 16 + ((lane >> 4) << 2);
#pragma unroll
            for (int j = 0; j < 4; ++j)
                out[(size_t)(rbase + j) * N_DIM + col] = acc[m][n][j] + bv;
        }
    }
}

// ---------------------------------------------------------------------------
extern "C" void kernel_launch(void* const* d_in, const int* in_sizes, int n_in,
                              void* d_out, int out_size, void* d_ws, size_t ws_size,
                              hipStream_t stream) {
    const float* x    = (const float*)d_in[0];  // [2,2048,4096]
    const float* w    = (const float*)d_in[1];  // [4096,4096]
    const float* bias = (const float*)d_in[2];  // [4096]
    const float* sA   = (const float*)d_in[3];  // [4096,4]
    const float* sB   = (const float*)d_in[4];  // [4,4096]
    const float* g    = (const float*)d_in[5];  // [4]
    float* out = (float*)d_out;

    // [weff bf16: 32MB][x_bf16: 32MB][tB f32: 64KB][tAg f32: 64KB]
    __hip_bfloat16* weff = (__hip_bfloat16*)d_ws;
    __hip_bfloat16* xb   = (__hip_bfloat16*)((char*)d_ws + (32ull << 20));
    float* tB  = (float*)((char*)d_ws + (64ull << 20));
    float* tAg = (float*)((char*)d_ws + (64ull << 20) + (R_DIM * K_DIM * 4));

    k_prep<<<dim3((2 * R_DIM * K_DIM) / 256), dim3(256), 0, stream>>>(sA, sB, g, tB, tAg);
    k_xcast<<<dim3((M_DIM * K_DIM) / (256 * 8)), dim3(256), 0, stream>>>(x, xb);
    k_weff<<<dim3(N_DIM), dim3(256), 0, stream>>>(w, tB, tAg, weff);
    k_gemm8<<<dim3((M_DIM / 256) * (N_DIM / 256)), dim3(512), 0, stream>>>(xb, weff, bias, out);
}